// Round 8
// baseline (12685.482 us; speedup 1.0000x reference)
//
#include <hip/hip_runtime.h>

// LSTM: T=1024, B=64, IN=H=512.
// Round 8 = Round 7 protocol + SOFTWARE-PIPELINED x-side.
//  Key change: x-waves (0-3) compute zx[t+1] during iteration t, reading x
//  A-fragments DIRECTLY from global (L2-cached, proven R0-R5 pattern) -- no
//  xlds, no x staging, x-GEMM fully off the h critical path (zx has no h
//  dependence). zx is parity double-buffered: write (t+1)&1, read t&1.
//  h-waves (4-7) unchanged from R7: poll flags -> load 32KB f16 ex slab
//  LLC-direct -> stage hlds -> 64-MFMA h-GEMM -> zh. setprio(1) on h-waves.
//  LDS traffic per WG-step drops 256KB+64KB-writes -> 128KB+32KB-writes.
//
//  Exchange (R5/R7 proven): producers cvt h->f16, WT-store (sc0 sc1) into
//  ex[parity t&1][grp][32][512]; drain; per-WG flag := t+1. Consumers at
//  iter t poll flags >= t then read parity (t-1)&1 LLC-direct (sc0 sc1 --
//  REQUIRED, addresses reused every other step so L2 could be stale).
//  Parity overwrite at t+2 is ordered after every consumer's read of t-data
//  because consumers post flag t+1 only after their read completed.
//  h_seq f32 out[t] is write-back (never read in-kernel).
// NOTE: all inline-asm async-load outputs EARLY-CLOBBER ("=&v") (round-2).

#define TT 1024
#define BB 64
#define DD 512
#define NWG 32
#define HSEQ ((size_t)TT * BB * DD)
#define EXOFF 4096   // byte offset of exchange slabs in d_ws

typedef _Float16 half8 __attribute__((ext_vector_type(8)));
typedef float f32x4 __attribute__((ext_vector_type(4)));
typedef float f32x2 __attribute__((ext_vector_type(2)));

__device__ __forceinline__ float sigm(float v) { return 1.0f / (1.0f + __expf(-v)); }
__device__ __forceinline__ float tanh_fast(float v) { return 2.0f / (1.0f + __expf(-2.0f * v)) - 1.0f; }

#define CVT8(DST, LO, HI) do { \
    DST[0] = (_Float16)LO[0]; DST[1] = (_Float16)LO[1]; \
    DST[2] = (_Float16)LO[2]; DST[3] = (_Float16)LO[3]; \
    DST[4] = (_Float16)HI[0]; DST[5] = (_Float16)HI[1]; \
    DST[6] = (_Float16)HI[2]; DST[7] = (_Float16)HI[3]; } while (0)

#define MFMA16(A, B, C) __builtin_amdgcn_mfma_f32_16x16x32_f16(A, B, C, 0, 0, 0)

// 8 batched LLC-direct 16B loads (one consumer thread's 128B share of the
// 32KB f16 h-slab), single vmcnt(0).
__device__ __forceinline__ void load_ex8(const char* base, f32x4 r[8]) {
    const char* p0 = base;
    const char* p1 = base + 4096;
    const char* p2 = base + 8192;
    const char* p3 = base + 12288;
    const char* p4 = base + 16384;
    const char* p5 = base + 20480;
    const char* p6 = base + 24576;
    const char* p7 = base + 28672;
    f32x4 a0, a1, a2, a3, a4, a5, a6, a7;
    asm volatile(
        "global_load_dwordx4 %0, %8, off sc0 sc1\n\t"
        "global_load_dwordx4 %1, %9, off sc0 sc1\n\t"
        "global_load_dwordx4 %2, %10, off sc0 sc1\n\t"
        "global_load_dwordx4 %3, %11, off sc0 sc1\n\t"
        "global_load_dwordx4 %4, %12, off sc0 sc1\n\t"
        "global_load_dwordx4 %5, %13, off sc0 sc1\n\t"
        "global_load_dwordx4 %6, %14, off sc0 sc1\n\t"
        "global_load_dwordx4 %7, %15, off sc0 sc1\n\t"
        "s_waitcnt vmcnt(0)"
        : "=&v"(a0), "=&v"(a1), "=&v"(a2), "=&v"(a3),
          "=&v"(a4), "=&v"(a5), "=&v"(a6), "=&v"(a7)
        : "v"(p0), "v"(p1), "v"(p2), "v"(p3), "v"(p4), "v"(p5), "v"(p6), "v"(p7)
        : "memory");
    r[0] = a0; r[1] = a1; r[2] = a2; r[3] = a3;
    r[4] = a4; r[5] = a5; r[6] = a6; r[7] = a7;
}

__global__ __launch_bounds__(512, 2) void lstm_persist(
    const float* __restrict__ x,
    const float* __restrict__ Wxf, const float* __restrict__ Whf,
    const float* __restrict__ Wxi, const float* __restrict__ Whi,
    const float* __restrict__ Wxo, const float* __restrict__ Who,
    const float* __restrict__ Wxg, const float* __restrict__ Whg,
    const float* __restrict__ bxf, const float* __restrict__ bhf,
    const float* __restrict__ bxi, const float* __restrict__ bhi,
    const float* __restrict__ bxo, const float* __restrict__ bho,
    const float* __restrict__ bxg, const float* __restrict__ bhg,
    float* __restrict__ out, int* __restrict__ flags, char* __restrict__ ex)
{
    const int wg   = blockIdx.x;     // 0..31
    const int grp  = wg >> 4;        // batch group 0..1
    const int w    = wg & 15;        // unit-block owner (32 units)
    const int tid  = threadIdx.x;    // 0..511
    const int wid  = tid >> 6;       // 0..7
    const int lane = tid & 63;
    const int quad = lane >> 4;
    const int l16  = lane & 15;
    const int g    = wid & 3;        // gate: 0=f 1=i 2=o 3=g
    const bool is_h = wid >= 4;
    const int sid  = tid & 255;      // id within side (0..255) for h staging

    __shared__ _Float16 hlds[32][520];   // h[t-1] slab, f16
    __shared__ float zx[2][4][32][34];   // x-side z, parity double-buffered
    __shared__ float zh[4][32][34];      // h-side z
    __shared__ float c_lds[32][34];      // persistent cell state
    __shared__ float bias_lds[4][32];    // bx+bh

    // ---- init c, zh(=0 for t=0), bias ----
    {
        const int e = tid * 2, b = e >> 5, u = e & 31;
        c_lds[b][u] = 0.0f; c_lds[b][u + 1] = 0.0f;
    }
    for (int i = tid; i < 4 * 32 * 34; i += 512) (&zh[0][0][0])[i] = 0.0f;
    if (tid < 128) {
        const int gg = tid >> 5, uu = tid & 31;
        const float* bx = (gg == 0) ? bxf : (gg == 1) ? bxi : (gg == 2) ? bxo : bxg;
        const float* bh = (gg == 0) ? bhf : (gg == 1) ? bhi : (gg == 2) ? bho : bhg;
        bias_lds[gg][uu] = bx[w * 32 + uu] + bh[w * 32 + uu];
    }

    // ---- weight B-fragments into registers (once): 2 n-tiles x 16 kc ----
    const float* Ws = !is_h
        ? ((g == 0) ? Wxf : (g == 1) ? Wxi : (g == 2) ? Wxo : Wxg)
        : ((g == 0) ? Whf : (g == 1) ? Whi : (g == 2) ? Who : Whg);
    half8 wfrag[2][16];
#pragma unroll
    for (int n = 0; n < 2; ++n)
#pragma unroll
        for (int kc = 0; kc < 16; ++kc) {
            const float* p = Ws + (size_t)(w * 32 + n * 16 + l16) * DD + kc * 32 + quad * 8;
            f32x4 lo = *(const f32x4*)p;
            f32x4 hi = *(const f32x4*)(p + 4);
            half8 f; CVT8(f, lo, hi);
            wfrag[n][kc] = f;
        }

    const float* xbase = x + (size_t)grp * 32 * DD;     // + t*BB*DD
    const int*   fb    = flags + grp * 16 + (lane & 15);
    char* exg = ex + ((size_t)grp << 15);               // 32KB group slab

    __syncthreads();

    // ---- prologue: x-waves compute zx[0] (step 0) ----
    if (!is_h) {
        const float* pa0 = xbase + (size_t)l16 * DD + quad * 8;    // x[0]
        const float* pa1 = pa0 + 16 * DD;
        f32x4 acc00 = {0,0,0,0}, acc01 = {0,0,0,0}, acc10 = {0,0,0,0}, acc11 = {0,0,0,0};
#pragma unroll
        for (int kc = 0; kc < 16; ++kc) {
            f32x4 a0lo = *(const f32x4*)(pa0 + kc * 32);
            f32x4 a0hi = *(const f32x4*)(pa0 + kc * 32 + 4);
            f32x4 a1lo = *(const f32x4*)(pa1 + kc * 32);
            f32x4 a1hi = *(const f32x4*)(pa1 + kc * 32 + 4);
            half8 a0, a1; CVT8(a0, a0lo, a0hi); CVT8(a1, a1lo, a1hi);
            acc00 = MFMA16(a0, wfrag[0][kc], acc00);
            acc01 = MFMA16(a0, wfrag[1][kc], acc01);
            acc10 = MFMA16(a1, wfrag[0][kc], acc10);
            acc11 = MFMA16(a1, wfrag[1][kc], acc11);
        }
#pragma unroll
        for (int i = 0; i < 4; ++i) {
            zx[0][g][quad * 4 + i][l16]           = acc00[i];
            zx[0][g][quad * 4 + i][16 + l16]      = acc01[i];
            zx[0][g][16 + quad * 4 + i][l16]      = acc10[i];
            zx[0][g][16 + quad * 4 + i][16 + l16] = acc11[i];
        }
    }
    __syncthreads();

    for (int t = 0; t < TT; ++t) {
        if (is_h) {
            __builtin_amdgcn_s_setprio(1);
            if (t > 0) {
                // wait for all 16 producers of this group (one 64B flag line)
                for (;;) {
                    int f;
                    asm volatile("global_load_dword %0, %1, off sc0 sc1\n\ts_waitcnt vmcnt(0)"
                                 : "=&v"(f) : "v"(fb) : "memory");
                    if (__all(f >= t)) break;
                    __builtin_amdgcn_s_sleep(1);
                }
                // h[t-1] f16 slab from exchange: 32KB coalesced LLC-direct
                const char* src = exg + (((t & 1) ^ 1) << 16) + sid * 16;
                f32x4 rr[8];
                load_ex8(src, rr);
#pragma unroll
                for (int i = 0; i < 8; ++i) {
                    const int flat = i * 2048 + sid * 8;   // f16 elems
                    const int r = flat >> 9, c = flat & 511;
                    union { f32x4 f; half8 h; } u; u.f = rr[i];
                    *(half8*)&hlds[r][c] = u.h;
                }
            }
        } else if (t + 1 < TT) {
            // ---- pipelined x-GEMM for step t+1, A direct from global ----
            const float* src = xbase + (size_t)(t + 1) * BB * DD;
            const float* pa0 = src + (size_t)l16 * DD + quad * 8;
            const float* pa1 = pa0 + 16 * DD;
            f32x4 acc00 = {0,0,0,0}, acc01 = {0,0,0,0}, acc10 = {0,0,0,0}, acc11 = {0,0,0,0};
#pragma unroll
            for (int kc = 0; kc < 16; ++kc) {
                f32x4 a0lo = *(const f32x4*)(pa0 + kc * 32);
                f32x4 a0hi = *(const f32x4*)(pa0 + kc * 32 + 4);
                f32x4 a1lo = *(const f32x4*)(pa1 + kc * 32);
                f32x4 a1hi = *(const f32x4*)(pa1 + kc * 32 + 4);
                half8 a0, a1; CVT8(a0, a0lo, a0hi); CVT8(a1, a1lo, a1hi);
                acc00 = MFMA16(a0, wfrag[0][kc], acc00);
                acc01 = MFMA16(a0, wfrag[1][kc], acc01);
                acc10 = MFMA16(a1, wfrag[0][kc], acc10);
                acc11 = MFMA16(a1, wfrag[1][kc], acc11);
            }
            float (*zb)[34] = zx[(t + 1) & 1][g];
#pragma unroll
            for (int i = 0; i < 4; ++i) {
                zb[quad * 4 + i][l16]           = acc00[i];
                zb[quad * 4 + i][16 + l16]      = acc01[i];
                zb[16 + quad * 4 + i][l16]      = acc10[i];
                zb[16 + quad * 4 + i][16 + l16] = acc11[i];
            }
        }
        __syncthreads();                               // (A) hlds + zx[t+1] done

        // ---- h-GEMM: 4 h-waves, 64 MFMA each ----
        if (is_h && t > 0) {
            f32x4 acc00 = {0,0,0,0}, acc01 = {0,0,0,0}, acc10 = {0,0,0,0}, acc11 = {0,0,0,0};
#pragma unroll
            for (int kc = 0; kc < 16; ++kc) {
                half8 a0 = *(const half8*)&hlds[l16][kc * 32 + quad * 8];
                half8 a1 = *(const half8*)&hlds[16 + l16][kc * 32 + quad * 8];
                acc00 = MFMA16(a0, wfrag[0][kc], acc00);
                acc01 = MFMA16(a0, wfrag[1][kc], acc01);
                acc10 = MFMA16(a1, wfrag[0][kc], acc10);
                acc11 = MFMA16(a1, wfrag[1][kc], acc11);
            }
#pragma unroll
            for (int i = 0; i < 4; ++i) {
                zh[g][quad * 4 + i][l16]           = acc00[i];
                zh[g][quad * 4 + i][16 + l16]      = acc01[i];
                zh[g][16 + quad * 4 + i][l16]      = acc10[i];
                zh[g][16 + quad * 4 + i][16 + l16] = acc11[i];
            }
        }
        if (is_h) __builtin_amdgcn_s_setprio(0);
        __syncthreads();                               // (B) zh complete

        // ---- elementwise: 512 threads x 2 (b,u) elems ----
        {
            const int e = tid * 2, b = e >> 5, u = e & 31;
            const float (*zxp)[32][34] = zx[t & 1];
            float h2[2];
#pragma unroll
            for (int k = 0; k < 2; ++k) {
                const int uu = u + k;
                float zf = bias_lds[0][uu] + zxp[0][b][uu] + zh[0][b][uu];
                float zi = bias_lds[1][uu] + zxp[1][b][uu] + zh[1][b][uu];
                float zo = bias_lds[2][uu] + zxp[2][b][uu] + zh[2][b][uu];
                float zg = bias_lds[3][uu] + zxp[3][b][uu] + zh[3][b][uu];
                float c  = sigm(zf) * c_lds[b][uu] + sigm(zi) * tanh_fast(zg);
                c_lds[b][uu] = c;
                h2[k] = sigm(zo) * tanh_fast(c);
            }
            // (a) f32 h_seq output: plain writeback store (not read in-kernel)
            float* hp = out + (size_t)t * BB * DD + (size_t)(grp * 32 + b) * DD + w * 32 + u;
            *(f32x2*)hp = (f32x2){h2[0], h2[1]};
            if (t == TT - 1) {
                float* fp2 = out + HSEQ + (size_t)(grp * 32 + b) * DD + w * 32 + u;
                fp2[0] = h2[0]; fp2[1] = h2[1];        // final h output
            }
            // (b) f16 exchange: 4B write-through, lands at LLC before flag
            union { _Float16 h[2]; unsigned u32; } pk;
            pk.h[0] = (_Float16)h2[0]; pk.h[1] = (_Float16)h2[1];
            char* dst = exg + ((t & 1) << 16)
                      + ((size_t)b * 512 + (w * 32 + u)) * 2;
            asm volatile("global_store_dword %0, %1, off sc0 sc1"
                         :: "v"(dst), "v"(pk.u32) : "memory");
        }
        // drain own stores, release
        asm volatile("s_waitcnt vmcnt(0)" ::: "memory");
        __syncthreads();                               // (C) all drained
        if (tid == 0) {
            int val = t + 1;
            int* fp = flags + grp * 16 + w;
            asm volatile("global_store_dword %0, %1, off sc0 sc1"
                         :: "v"(fp), "v"(val) : "memory");
        }
    }

    // ---- final c output ----
    {
        const int e = tid * 2, b = e >> 5, u = e & 31;
        float* cp = out + HSEQ + (size_t)BB * DD + (size_t)(grp * 32 + b) * DD + w * 32 + u;
        cp[0] = c_lds[b][u];
        cp[1] = c_lds[b][u + 1];
    }
}

extern "C" void kernel_launch(void* const* d_in, const int* in_sizes, int n_in,
                              void* d_out, int out_size, void* d_ws, size_t ws_size,
                              hipStream_t stream) {
    const float* x   = (const float*)d_in[0];
    const float* Wxf = (const float*)d_in[1];  const float* bxf = (const float*)d_in[2];
    const float* Whf = (const float*)d_in[3];  const float* bhf = (const float*)d_in[4];
    const float* Wxi = (const float*)d_in[5];  const float* bxi = (const float*)d_in[6];
    const float* Whi = (const float*)d_in[7];  const float* bhi = (const float*)d_in[8];
    const float* Wxo = (const float*)d_in[9];  const float* bxo = (const float*)d_in[10];
    const float* Who = (const float*)d_in[11]; const float* bho = (const float*)d_in[12];
    const float* Wxg = (const float*)d_in[13]; const float* bxg = (const float*)d_in[14];
    const float* Whg = (const float*)d_in[15]; const float* bhg = (const float*)d_in[16];
    float* out = (float*)d_out;
    int* flags = (int*)d_ws;
    // ex: [parity 0/1][grp 0/1][32 b][512 u] f16; parity stride 64KB,
    // group stride 32KB. Total 128KB at d_ws+4KB.
    char* ex = (char*)d_ws + EXOFF;

    // flags are poisoned 0xAA before every timed launch -> zero them.
    // (ex needs no init: parity p is fully written at step t (p=t&1) before
    //  any read of it at step t+1)
    hipMemsetAsync(d_ws, 0, (size_t)NWG * sizeof(int), stream);

    void* args[] = { &x,
                     &Wxf, &Whf, &Wxi, &Whi, &Wxo, &Who, &Wxg, &Whg,
                     &bxf, &bhf, &bxi, &bhi, &bxo, &bho, &bxg, &bhg,
                     &out, &flags, &ex };
    hipLaunchCooperativeKernel((const void*)lstm_persist,
                               dim3(NWG), dim3(512), args, 0, stream);
}